// Round 1
// baseline (1665.389 us; speedup 1.0000x reference)
//
#include <hip/hip_runtime.h>

// MS-G3D block, fp32 baseline.
// Shapes: N=8, C=96, T=128, V=25, WIN=3, VL=75, NS=6, DIN=1152.
// ws layout (floats):
//   h_relu  : [0, 7372800)                 (N,C,T,VL) post-MLP relu
//   out_pre : [7372800, 9830400)           (N,C,T,V) pre-BN2
//   AB      : [9830400, +67575)            [path][450][75] (+75 pad row)
//   stats   : [.., +384)                   s1[96],sq1[96], s2[96],sq2[96]

#define NB 8
#define CB 96
#define TB 128
#define VB 25
#define VLB 75
#define EPSB 1e-5f

// ---------------- K0: AB = scales + res, zero stats ----------------
__global__ __launch_bounds__(256) void k0_init(
    const float* __restrict__ As, const float* __restrict__ Bs,
    const float* __restrict__ Ar, float* __restrict__ AB,
    float* __restrict__ stats) {
  int i = blockIdx.x * 256 + threadIdx.x;
  if (i < 450 * 75) {
    AB[i]           = As[i] + Ar[i];
    AB[33750 + i]   = Bs[i] + Ar[i];
  }
  if (i < 384) stats[i] = 0.f;
}

// ---------------- K1: unfold + MLP + agg + relu + BN1 stats ----------------
// grid = N*T = 1024 blocks, 384 threads.
// thread: o = tid%96, g = tid/4? -> g = tid/96 in [0,4)
//   phase A: computes tmp[o][u'] for u' in [g*19, g*19+19)
//   phase B: owns h2[o][u] for u = g + 4k, k<19 (g==3 -> 18 valid)
__global__ __launch_bounds__(384) void k1_agg_mlp(
    const float* __restrict__ x, const float* __restrict__ AB,
    const float* __restrict__ Wm, const float* __restrict__ bm,
    float* __restrict__ h_relu, float* __restrict__ stats1) {
  __shared__ float xu_s[96][77];   // unfolded input tile, stride 77 (conflict-free)
  __shared__ float tmp_s[96][77];  // per-phase MLP output
  const int tid = threadIdx.x;
  const int n = blockIdx.x >> 7, t = blockIdx.x & 127;

  for (int idx = tid; idx < 96 * 75; idx += 384) {
    int c = idx / 75, u = idx % 75;
    int w = u / 25, v = u % 25;
    int tt = t + w - 1;
    xu_s[c][u] = (tt >= 0 && tt < TB) ? x[((n * CB + c) * TB + tt) * VB + v] : 0.f;
  }
  __syncthreads();

  const int o = tid % 96;
  const int g = tid / 96;        // 0..3
  const int u0 = g * 19;         // phase-A column base (reads up to u0+18 <= 75, in-row pad ok)

  float hacc[19];
#pragma unroll
  for (int k = 0; k < 19; ++k) hacc[k] = 0.f;

  for (int ps = 0; ps < 12; ++ps) {      // ps = path*6 + s;  W column block = ps*96
    const int path = ps / 6, s = ps % 6;
    const float* wrow = Wm + o * 1152 + ps * 96;

    float acc[19];
#pragma unroll
    for (int j = 0; j < 19; ++j) acc[j] = 0.f;
    for (int c = 0; c < 96; ++c) {
      float wv = wrow[c];
#pragma unroll
      for (int j = 0; j < 19; ++j) acc[j] += wv * xu_s[c][u0 + j];
    }
    __syncthreads();                     // prev phase-B readers done with tmp_s
#pragma unroll
    for (int j = 0; j < 19; ++j) tmp_s[o][u0 + j] = acc[j];
    __syncthreads();

    // h2[o][g+4k] += AB[path][s*75 + u][u'] * tmp[o][u']
    const float* ABs = AB + path * 33750 + (s * 75 + g) * 75;  // row for k=0; +300 per k
    for (int up = 0; up < 75; ++up) {
      float tv = tmp_s[o][up];
      const float* ap = ABs + up;
#pragma unroll
      for (int k = 0; k < 19; ++k) hacc[k] += ap[k * 300] * tv;  // k*4 rows * 75
    }
  }

  // epilogue: bias + relu + store + BN1 partial stats
  float s1 = 0.f, s2 = 0.f;
  const float bias = bm[o];
#pragma unroll
  for (int k = 0; k < 19; ++k) {
    int u = g + 4 * k;
    if (u < 75) {
      float v = hacc[k] + bias;
      v = v > 0.f ? v : 0.f;
      h_relu[((n * CB + o) * TB + t) * VLB + u] = v;
      s1 += v;
      s2 += v * v;
    }
  }
  __syncthreads();
  xu_s[o][g] = s1;
  xu_s[o][g + 4] = s2;
  __syncthreads();
  if (tid < 96) {
    float a = xu_s[tid][0] + xu_s[tid][1] + xu_s[tid][2] + xu_s[tid][3];
    float b = xu_s[tid][4] + xu_s[tid][5] + xu_s[tid][6] + xu_s[tid][7];
    atomicAdd(&stats1[tid], a);
    atomicAdd(&stats1[96 + tid], b);
  }
}

// ---------------- K3: BN1-finalize + relu + out_conv + BN2 stats ----------------
// grid = N*T = 1024 blocks, 256 threads.
__global__ __launch_bounds__(256) void k3_outconv(
    const float* __restrict__ h_relu, const float* __restrict__ stats1,
    const float* __restrict__ g1, const float* __restrict__ bt1,
    const float* __restrict__ Wo, const float* __restrict__ bo,
    float* __restrict__ out_pre, float* __restrict__ stats2) {
  __shared__ float hn[96][77];
  __shared__ float a1s[96], b1s[96];
  __shared__ float st[192];
  const int tid = threadIdx.x;
  const int n = blockIdx.x >> 7, t = blockIdx.x & 127;

  if (tid < 96) {
    const float inv = 1.f / (8.f * 128.f * 75.f);
    float m = stats1[tid] * inv;
    float var = stats1[96 + tid] * inv - m * m;
    float a = g1[tid] * rsqrtf(var + EPSB);
    a1s[tid] = a;
    b1s[tid] = bt1[tid] - m * a;
  }
  if (tid < 192) st[tid] = 0.f;
  __syncthreads();

  for (int idx = tid; idx < 96 * 75; idx += 256) {
    int i = idx / 75, u = idx % 75;
    float hv = h_relu[((n * CB + i) * TB + t) * VLB + u];
    float v = a1s[i] * hv + b1s[i];
    hn[i][u] = v > 0.f ? v : 0.f;
  }
  __syncthreads();

  for (int idx = tid; idx < 96 * 25; idx += 256) {
    int o = idx / 25, v = idx % 25;
    float acc = bo[o];
    const float* wp = Wo + o * 96 * 3;
    for (int i = 0; i < 96; ++i) {
      acc += wp[i * 3 + 0] * hn[i][v]
           + wp[i * 3 + 1] * hn[i][25 + v]
           + wp[i * 3 + 2] * hn[i][50 + v];
    }
    out_pre[((n * CB + o) * TB + t) * VB + v] = acc;
    atomicAdd(&st[o], acc);
    atomicAdd(&st[96 + o], acc * acc);
  }
  __syncthreads();
  if (tid < 96) {
    atomicAdd(&stats2[tid], st[tid]);
    atomicAdd(&stats2[96 + tid], st[96 + tid]);
  }
}

// ---------------- K5: BN2 finalize (elementwise) ----------------
__global__ __launch_bounds__(256) void k5_bn2(
    const float* __restrict__ out_pre, const float* __restrict__ stats2,
    const float* __restrict__ g2, const float* __restrict__ bt2,
    float* __restrict__ out) {
  int idx = blockIdx.x * 256 + threadIdx.x;
  if (idx >= NB * CB * TB * VB) return;
  int o = (idx / (TB * VB)) % CB;
  const float inv = 1.f / (8.f * 128.f * 25.f);
  float m = stats2[o] * inv;
  float var = stats2[96 + o] * inv - m * m;
  float a = g2[o] * rsqrtf(var + EPSB);
  float b = bt2[o] - m * a;
  out[idx] = a * out_pre[idx] + b;
}

extern "C" void kernel_launch(void* const* d_in, const int* in_sizes, int n_in,
                              void* d_out, int out_size, void* d_ws, size_t ws_size,
                              hipStream_t stream) {
  const float* x   = (const float*)d_in[0];
  const float* As  = (const float*)d_in[1];
  const float* Bs  = (const float*)d_in[2];
  const float* Ar  = (const float*)d_in[3];
  const float* Wm  = (const float*)d_in[4];
  const float* bm  = (const float*)d_in[5];
  const float* g1  = (const float*)d_in[6];
  const float* bt1 = (const float*)d_in[7];
  const float* Wo  = (const float*)d_in[8];
  const float* bo  = (const float*)d_in[9];
  const float* g2  = (const float*)d_in[10];
  const float* bt2 = (const float*)d_in[11];

  float* ws      = (float*)d_ws;
  float* h_relu  = ws;                       // 7,372,800
  float* out_pre = ws + 7372800;             // 2,457,600
  float* AB      = ws + 9830400;             // 67,500 (+75 pad)
  float* stats   = ws + 9830400 + 67575;     // 384
  float* stats1  = stats;
  float* stats2  = stats + 192;
  float* out     = (float*)d_out;

  k0_init<<<(33750 + 255) / 256, 256, 0, stream>>>(As, Bs, Ar, AB, stats);
  k1_agg_mlp<<<NB * TB, 384, 0, stream>>>(x, AB, Wm, bm, h_relu, stats1);
  k3_outconv<<<NB * TB, 256, 0, stream>>>(h_relu, stats1, g1, bt1, Wo, bo, out_pre, stats2);
  k5_bn2<<<(NB * CB * TB * VB + 255) / 256, 256, 0, stream>>>(out_pre, stats2, g2, bt2, out);
}

// Round 2
// 368.082 us; speedup vs baseline: 4.5245x; 4.5245x over previous
//
#include <hip/hip_runtime.h>

// MS-G3D block. bf16-MFMA main kernel, fp32 elsewhere.
// N=8, C=96, T=128, V=25, WIN=3, VL=75, NS=6.
// ws layout (float units):
//   h_relu  : [0, 7372800)            (N,C,T,75) post-MLP relu (fp32)
//   out_pre : [7372800, 9830400)      (N,C,T,25) pre-BN2
//   ABbf    : ushort at 9830400       12 x [80 u][96 u'] bf16 (zero-padded)
//   Wbf     : ushort, next            12 x [96 o][96 c] bf16
//   stats   : float, next             s1[96] sq1[96] s2[96] sq2[96]

#define NB 8
#define CB 96
#define TB 128
#define VB 25
#define VLB 75
#define EPSB 1e-5f
#define XUP 104   // xu_t row stride (shorts): 13*8 -> 16B-aligned frags, 2-way banks
#define TMP 104   // tmp_s row stride

typedef __attribute__((ext_vector_type(8))) short bf16x8;
typedef __attribute__((ext_vector_type(4))) float f32x4;

__device__ inline unsigned short f2bf(float f) {
  unsigned int u = __float_as_uint(f);
  u = (u + 0x7FFFu + ((u >> 16) & 1u)) >> 16;
  return (unsigned short)u;
}

// ---------------- K0: pre-cast W and AB to bf16 tiles; zero stats ----------------
__global__ __launch_bounds__(256) void k0_init(
    const float* __restrict__ As, const float* __restrict__ Bs,
    const float* __restrict__ Ar, const float* __restrict__ Wm,
    unsigned short* __restrict__ ABbf, unsigned short* __restrict__ Wbf,
    float* __restrict__ stats) {
  int i = blockIdx.x * 256 + threadIdx.x;
  if (i < 12 * 96 * 96) {                       // Wbf[ps][o][c]
    int ps = i / 9216, rem = i % 9216, o = rem / 96, c = rem % 96;
    Wbf[i] = f2bf(Wm[o * 1152 + ps * 96 + c]);
  }
  if (i < 12 * 80 * 96) {                       // ABbf[ps][u][u'] (n-major, k=u' contiguous)
    int ps = i / 7680, rem = i % 7680, u = rem / 96, up = rem % 96;
    float v = 0.f;
    if (u < 75 && up < 75) {
      int path = ps / 6, s = ps % 6;
      int idx = (s * 75 + u) * 75 + up;
      v = (path == 0 ? As[idx] : Bs[idx]) + Ar[idx];
    }
    ABbf[i] = f2bf(v);
  }
  if (i < 384) stats[i] = 0.f;
}

// ---------------- K1: unfold + (MLP GEMM -> agg GEMM) x12 via MFMA + BN1 stats ----
// grid = N*T = 1024 blocks, 384 threads (6 waves). Wave w owns out rows [16w,16w+16).
__global__ __launch_bounds__(384) void k1_mfma(
    const float* __restrict__ x, const unsigned short* __restrict__ ABbf,
    const unsigned short* __restrict__ Wbf, const float* __restrict__ bm,
    float* __restrict__ h_relu, float* __restrict__ stats1) {
  __shared__ unsigned short xu_t[80 * XUP];   // [u'][c] bf16, rows 75..79 zero
  __shared__ unsigned short tmp_s[96 * TMP];  // [o][u'] bf16, cols 80..103 zero
  __shared__ float st1s[96], st2s[96];
  const int tid = threadIdx.x;
  const int n = blockIdx.x >> 7, t = blockIdx.x & 127;
  const int wave = tid >> 6, lane = tid & 63;
  const int l15 = lane & 15, quad = lane >> 4, q8 = quad * 8;

  // stage xu_t[u'][c] = x[n][c][t + u'/25 - 1][u'%25]; zero pad rows
  for (int idx = tid; idx < 96 * 80; idx += 384) {
    int c = idx / 80, up = idx % 80;
    float v = 0.f;
    if (up < 75) {
      int w = up / 25, vv = up % 25, tt = t + w - 1;
      if (tt >= 0 && tt < TB) v = x[((n * CB + c) * TB + tt) * VB + vv];
    }
    xu_t[up * XUP + c] = f2bf(v);
  }
  // zero tmp_s pad cols [80,104) once (read as K-pad; must not be NaN)
  for (int idx = tid; idx < 96 * 24; idx += 384) {
    int r = idx / 24, cc = 80 + idx % 24;
    tmp_s[r * TMP + cc] = 0;
  }
  __syncthreads();

  const f32x4 zf = {0.f, 0.f, 0.f, 0.f};
  f32x4 acc2[5];
#pragma unroll
  for (int nt = 0; nt < 5; ++nt) acc2[nt] = zf;

  for (int ps = 0; ps < 12; ++ps) {
    const unsigned short* Wp = Wbf + ps * 9216 + (wave * 16 + l15) * 96 + q8;
    const unsigned short* Bp = ABbf + ps * 7680 + l15 * 96 + q8;

    // GEMM1: tmp[o,u'] = sum_c W_ps[o,c] * xu[c,u']   (K=96)
    f32x4 acc1[5];
#pragma unroll
    for (int nt = 0; nt < 5; ++nt) acc1[nt] = zf;
#pragma unroll
    for (int kk = 0; kk < 3; ++kk) {
      bf16x8 a = *reinterpret_cast<const bf16x8*>(Wp + kk * 32);
#pragma unroll
      for (int nt = 0; nt < 5; ++nt) {
        bf16x8 b = *reinterpret_cast<const bf16x8*>(&xu_t[(nt * 16 + l15) * XUP + kk * 32 + q8]);
        acc1[nt] = __builtin_amdgcn_mfma_f32_16x16x32_bf16(a, b, acc1[nt], 0, 0, 0);
      }
    }
    // C-layout -> A-layout via LDS; rows [16w,16w+16) are wave-private: no barrier
#pragma unroll
    for (int nt = 0; nt < 5; ++nt)
#pragma unroll
      for (int r = 0; r < 4; ++r)
        tmp_s[(wave * 16 + quad * 4 + r) * TMP + nt * 16 + l15] = f2bf(acc1[nt][r]);

    // GEMM2: h[o,u] += sum_u' tmp[o,u'] * AB_ps[u,u']   (K=75 padded to 96)
#pragma unroll
    for (int kk = 0; kk < 3; ++kk) {
      bf16x8 a2 = *reinterpret_cast<const bf16x8*>(&tmp_s[(wave * 16 + l15) * TMP + kk * 32 + q8]);
#pragma unroll
      for (int nt = 0; nt < 5; ++nt) {
        bf16x8 b2 = *reinterpret_cast<const bf16x8*>(Bp + nt * 16 * 96 + kk * 32);
        acc2[nt] = __builtin_amdgcn_mfma_f32_16x16x32_bf16(a2, b2, acc2[nt], 0, 0, 0);
      }
    }
  }

  // epilogue: bias + relu + store + BN1 partial stats
  const int orow = wave * 16 + quad * 4;
  float s1[4] = {0.f, 0.f, 0.f, 0.f}, s2[4] = {0.f, 0.f, 0.f, 0.f};
#pragma unroll
  for (int r = 0; r < 4; ++r) {
    const int o = orow + r;
    const float bias = bm[o];
    float* hp = h_relu + ((n * CB + o) * TB + t) * VLB;
#pragma unroll
    for (int nt = 0; nt < 5; ++nt) {
      int u = nt * 16 + l15;
      if (u < VLB) {
        float v = acc2[nt][r] + bias;
        v = v > 0.f ? v : 0.f;
        hp[u] = v;
        s1[r] += v;
        s2[r] += v * v;
      }
    }
  }
#pragma unroll
  for (int off = 1; off < 16; off <<= 1) {
#pragma unroll
    for (int r = 0; r < 4; ++r) {
      s1[r] += __shfl_xor(s1[r], off, 64);
      s2[r] += __shfl_xor(s2[r], off, 64);
    }
  }
  if (l15 == 0) {
#pragma unroll
    for (int r = 0; r < 4; ++r) { st1s[orow + r] = s1[r]; st2s[orow + r] = s2[r]; }
  }
  __syncthreads();
  if (tid < 96) {
    atomicAdd(&stats1[tid], st1s[tid]);
    atomicAdd(&stats1[96 + tid], st2s[tid]);
  }
}

// ---------------- K3: BN1-finalize + relu + out_conv + BN2 stats ----------------
__global__ __launch_bounds__(256) void k3_outconv(
    const float* __restrict__ h_relu, const float* __restrict__ stats1,
    const float* __restrict__ g1, const float* __restrict__ bt1,
    const float* __restrict__ Wo, const float* __restrict__ bo,
    float* __restrict__ out_pre, float* __restrict__ stats2) {
  __shared__ float hn[96][77];
  __shared__ float a1s[96], b1s[96];
  __shared__ float st[192];
  const int tid = threadIdx.x;
  const int n = blockIdx.x >> 7, t = blockIdx.x & 127;

  if (tid < 96) {
    const float inv = 1.f / (8.f * 128.f * 75.f);
    float m = stats1[tid] * inv;
    float var = stats1[96 + tid] * inv - m * m;
    float a = g1[tid] * rsqrtf(var + EPSB);
    a1s[tid] = a;
    b1s[tid] = bt1[tid] - m * a;
  }
  if (tid < 192) st[tid] = 0.f;
  __syncthreads();

  for (int idx = tid; idx < 96 * 75; idx += 256) {
    int i = idx / 75, u = idx % 75;
    float hv = h_relu[((n * CB + i) * TB + t) * VLB + u];
    float v = a1s[i] * hv + b1s[i];
    hn[i][u] = v > 0.f ? v : 0.f;
  }
  __syncthreads();

  for (int idx = tid; idx < 96 * 25; idx += 256) {
    int o = idx / 25, v = idx % 25;
    float acc = bo[o];
    const float* wp = Wo + o * 96 * 3;
    for (int i = 0; i < 96; ++i) {
      acc += wp[i * 3 + 0] * hn[i][v]
           + wp[i * 3 + 1] * hn[i][25 + v]
           + wp[i * 3 + 2] * hn[i][50 + v];
    }
    out_pre[((n * CB + o) * TB + t) * VB + v] = acc;
    atomicAdd(&st[o], acc);
    atomicAdd(&st[96 + o], acc * acc);
  }
  __syncthreads();
  if (tid < 96) {
    atomicAdd(&stats2[tid], st[tid]);
    atomicAdd(&stats2[96 + tid], st[96 + tid]);
  }
}

// ---------------- K5: BN2 finalize (elementwise) ----------------
__global__ __launch_bounds__(256) void k5_bn2(
    const float* __restrict__ out_pre, const float* __restrict__ stats2,
    const float* __restrict__ g2, const float* __restrict__ bt2,
    float* __restrict__ out) {
  int idx = blockIdx.x * 256 + threadIdx.x;
  if (idx >= NB * CB * TB * VB) return;
  int o = (idx / (TB * VB)) % CB;
  const float inv = 1.f / (8.f * 128.f * 25.f);
  float m = stats2[o] * inv;
  float var = stats2[96 + o] * inv - m * m;
  float a = g2[o] * rsqrtf(var + EPSB);
  float b = bt2[o] - m * a;
  out[idx] = a * out_pre[idx] + b;
}

extern "C" void kernel_launch(void* const* d_in, const int* in_sizes, int n_in,
                              void* d_out, int out_size, void* d_ws, size_t ws_size,
                              hipStream_t stream) {
  const float* x   = (const float*)d_in[0];
  const float* As  = (const float*)d_in[1];
  const float* Bs  = (const float*)d_in[2];
  const float* Ar  = (const float*)d_in[3];
  const float* Wm  = (const float*)d_in[4];
  const float* bm  = (const float*)d_in[5];
  const float* g1  = (const float*)d_in[6];
  const float* bt1 = (const float*)d_in[7];
  const float* Wo  = (const float*)d_in[8];
  const float* bo  = (const float*)d_in[9];
  const float* g2  = (const float*)d_in[10];
  const float* bt2 = (const float*)d_in[11];

  float* ws      = (float*)d_ws;
  float* h_relu  = ws;                                   // 7,372,800 f
  float* out_pre = ws + 7372800;                         // 2,457,600 f
  unsigned short* ABbf = (unsigned short*)(ws + 9830400);  // 92,160 us
  unsigned short* Wbf  = ABbf + 92160;                     // 110,592 us
  float* stats   = (float*)(Wbf + 110592);               // 384 f
  float* stats1  = stats;
  float* stats2  = stats + 192;
  float* out     = (float*)d_out;

  k0_init<<<(12 * 96 * 96 + 255) / 256, 256, 0, stream>>>(As, Bs, Ar, Wm, ABbf, Wbf, stats);
  k1_mfma<<<NB * TB, 384, 0, stream>>>(x, ABbf, Wbf, bm, h_relu, stats1);
  k3_outconv<<<NB * TB, 256, 0, stream>>>(h_relu, stats1, g1, bt1, Wo, bo, out_pre, stats2);
  k5_bn2<<<(NB * CB * TB * VB + 255) / 256, 256, 0, stream>>>(out_pre, stats2, g2, bt2, out);
}

// Round 3
// 290.585 us; speedup vs baseline: 5.7312x; 1.2667x over previous
//
#include <hip/hip_runtime.h>

// MS-G3D block. bf16-MFMA k1 (t-chunk=2) + bf16-MFMA k3 out_conv.
// N=8, C=96, T=128, V=25, WIN=3, VL=75, NS=6.

#define NB 8
#define CB 96
#define TB 128
#define VB 25
#define VLB 75
#define EPSB 1e-5f
#define XRS 104   // xraw row stride (shorts) -> 208B rows, 16B-aligned, 2-way banks
#define TMS 104   // tmp row stride
#define HBS 296   // hnb row stride (shorts) -> 592B rows, 16B-aligned

typedef __attribute__((ext_vector_type(8))) short bf16x8;
typedef __attribute__((ext_vector_type(4))) float f32x4;

__device__ inline unsigned short f2bf(float f) {
  unsigned int u = __float_as_uint(f);
  u = (u + 0x7FFFu + ((u >> 16) & 1u)) >> 16;
  return (unsigned short)u;
}

// ---------------- K0: pre-cast W, AB, Wo to bf16; zero stats ----------------
__global__ __launch_bounds__(256) void k0_init(
    const float* __restrict__ As, const float* __restrict__ Bs,
    const float* __restrict__ Ar, const float* __restrict__ Wm,
    const float* __restrict__ Wo,
    unsigned short* __restrict__ ABbf, unsigned short* __restrict__ Wbf,
    unsigned short* __restrict__ Wobf, float* __restrict__ stats) {
  int i = blockIdx.x * 256 + threadIdx.x;
  if (i < 12 * 96 * 96) {                       // Wbf[ps][o][c]
    int ps = i / 9216, rem = i % 9216, o = rem / 96, c = rem % 96;
    Wbf[i] = f2bf(Wm[o * 1152 + ps * 96 + c]);
  }
  if (i < 12 * 80 * 96) {                       // ABbf[ps][u][u'] (n-major, k contiguous)
    int ps = i / 7680, rem = i % 7680, u = rem / 96, up = rem % 96;
    float v = 0.f;
    if (u < 75 && up < 75) {
      int path = ps / 6, s = ps % 6;
      int idx = (s * 75 + u) * 75 + up;
      v = (path == 0 ? As[idx] : Bs[idx]) + Ar[idx];
    }
    ABbf[i] = f2bf(v);
  }
  if (i < 96 * 288) Wobf[i] = f2bf(Wo[i]);      // (o,i,w) flat == [o][i*3+w]
  if (i < 384) stats[i] = 0.f;
}

// ---------------- K1: unfold + (MLP -> agg) x12 MFMA, 2 t per block ----------
// grid = N*T/2 = 512 blocks, 384 threads (6 waves). Wave w owns o-rows [16w,16w+16).
__global__ __launch_bounds__(384, 3) void k1_mfma(
    const float* __restrict__ x, const unsigned short* __restrict__ ABbf,
    const unsigned short* __restrict__ Wbf, const float* __restrict__ bm,
    float* __restrict__ h_relu, float* __restrict__ stats1) {
  __shared__ unsigned short xraw[112 * XRS];     // [r=(tt_rel*25+v)][c], rows 100..111 zero
  __shared__ unsigned short tmp_s[2][96 * TMS];  // per-dt tmp [o][u'], cols 80..103 zero
  __shared__ float st1s[96], st2s[96];
  const int tid = threadIdx.x;
  const int n = blockIdx.x >> 6, t0 = (blockIdx.x & 63) * 2;
  const int wave = tid >> 6, lane = tid & 63;
  const int l15 = lane & 15, quad = lane >> 4, q8 = quad * 8;

  // stage raw x slice: tt = t0-1 .. t0+2 (4 windows = 100 rows), zero-pad to 112
  for (int idx = tid; idx < 96 * 112; idx += 384) {
    int c = idx / 112, r = idx - c * 112;
    float v = 0.f;
    if (r < 100) {
      int tt = t0 - 1 + r / 25, vv = r % 25;
      if (tt >= 0 && tt < TB) v = x[((n * CB + c) * TB + tt) * VB + vv];
    }
    xraw[r * XRS + c] = f2bf(v);
  }
  for (int idx = tid; idx < 2 * 96 * 24; idx += 384) {  // zero K-pad cols of tmp
    int b = idx / (96 * 24), rem = idx - b * 96 * 24;
    tmp_s[b][(rem / 24) * TMS + 80 + rem % 24] = 0;
  }
  __syncthreads();

  const f32x4 zf = {0.f, 0.f, 0.f, 0.f};
  f32x4 acc2[2][5];
#pragma unroll
  for (int d = 0; d < 2; ++d)
#pragma unroll
    for (int nt = 0; nt < 5; ++nt) acc2[d][nt] = zf;

  for (int ps = 0; ps < 12; ++ps) {
    const unsigned short* Wp = Wbf + ps * 9216 + (wave * 16 + l15) * 96 + q8;
    bf16x8 wa[3];
#pragma unroll
    for (int kk = 0; kk < 3; ++kk) wa[kk] = *reinterpret_cast<const bf16x8*>(Wp + kk * 32);

    // GEMM1 for both dt: tmp_d[o,u'] = sum_c W_ps[o,c] xu_d[c,u']
    f32x4 acc1[2][5];
#pragma unroll
    for (int d = 0; d < 2; ++d)
#pragma unroll
      for (int nt = 0; nt < 5; ++nt) acc1[d][nt] = zf;
#pragma unroll
    for (int kk = 0; kk < 3; ++kk) {
#pragma unroll
      for (int nt = 0; nt < 5; ++nt) {
        bf16x8 b0 = *reinterpret_cast<const bf16x8*>(&xraw[(nt * 16 + l15) * XRS + kk * 32 + q8]);
        bf16x8 b1 = *reinterpret_cast<const bf16x8*>(&xraw[(25 + nt * 16 + l15) * XRS + kk * 32 + q8]);
        acc1[0][nt] = __builtin_amdgcn_mfma_f32_16x16x32_bf16(wa[kk], b0, acc1[0][nt], 0, 0, 0);
        acc1[1][nt] = __builtin_amdgcn_mfma_f32_16x16x32_bf16(wa[kk], b1, acc1[1][nt], 0, 0, 0);
      }
    }
    // C->A layout via LDS; wave-private rows: no barrier. Mask cols >=75 to 0.
#pragma unroll
    for (int d = 0; d < 2; ++d)
#pragma unroll
      for (int nt = 0; nt < 5; ++nt) {
        int col = nt * 16 + l15;
#pragma unroll
        for (int r = 0; r < 4; ++r) {
          unsigned short v = (col < 75) ? f2bf(acc1[d][nt][r]) : (unsigned short)0;
          tmp_s[d][(wave * 16 + quad * 4 + r) * TMS + col] = v;
        }
      }
    // GEMM2: h_d[o,u] += sum_u' tmp_d[o,u'] AB_ps[u,u']; B-frags reused across dt
    const unsigned short* Bp = ABbf + ps * 7680 + l15 * 96 + q8;
#pragma unroll
    for (int kk = 0; kk < 3; ++kk) {
      bf16x8 a0 = *reinterpret_cast<const bf16x8*>(&tmp_s[0][(wave * 16 + l15) * TMS + kk * 32 + q8]);
      bf16x8 a1 = *reinterpret_cast<const bf16x8*>(&tmp_s[1][(wave * 16 + l15) * TMS + kk * 32 + q8]);
#pragma unroll
      for (int nt = 0; nt < 5; ++nt) {
        bf16x8 b2 = *reinterpret_cast<const bf16x8*>(Bp + nt * 16 * 96 + kk * 32);
        acc2[0][nt] = __builtin_amdgcn_mfma_f32_16x16x32_bf16(a0, b2, acc2[0][nt], 0, 0, 0);
        acc2[1][nt] = __builtin_amdgcn_mfma_f32_16x16x32_bf16(a1, b2, acc2[1][nt], 0, 0, 0);
      }
    }
  }

  // epilogue: bias + relu + store + BN1 partial stats (both dt)
  const int orow = wave * 16 + quad * 4;
  float s1[4] = {0.f, 0.f, 0.f, 0.f}, s2[4] = {0.f, 0.f, 0.f, 0.f};
#pragma unroll
  for (int d = 0; d < 2; ++d) {
    const int t = t0 + d;
#pragma unroll
    for (int r = 0; r < 4; ++r) {
      const int o = orow + r;
      const float bias = bm[o];
      float* hp = h_relu + ((n * CB + o) * TB + t) * VLB;
#pragma unroll
      for (int nt = 0; nt < 5; ++nt) {
        int u = nt * 16 + l15;
        if (u < VLB) {
          float v = acc2[d][nt][r] + bias;
          v = v > 0.f ? v : 0.f;
          hp[u] = v;
          s1[r] += v;
          s2[r] += v * v;
        }
      }
    }
  }
#pragma unroll
  for (int off = 1; off < 16; off <<= 1) {
#pragma unroll
    for (int r = 0; r < 4; ++r) {
      s1[r] += __shfl_xor(s1[r], off, 64);
      s2[r] += __shfl_xor(s2[r], off, 64);
    }
  }
  if (l15 == 0) {
#pragma unroll
    for (int r = 0; r < 4; ++r) { st1s[orow + r] = s1[r]; st2s[orow + r] = s2[r]; }
  }
  __syncthreads();
  if (tid < 96) {
    atomicAdd(&stats1[tid], st1s[tid]);
    atomicAdd(&stats1[96 + tid], st2s[tid]);
  }
}

// ---------------- K3: BN1-finalize + relu + out_conv (MFMA) + BN2 stats ------
// grid = N*T = 1024 blocks, 384 threads (6 waves). Wave w owns o-rows [16w,16w+16).
// out[o,v] = sum_{i,w} Wo[o, i*3+w] * hn[i, w*25+v]   (K = 288 = 9*32 exact)
__global__ __launch_bounds__(384) void k3_outconv(
    const float* __restrict__ h_relu, const float* __restrict__ stats1,
    const float* __restrict__ g1, const float* __restrict__ bt1,
    const unsigned short* __restrict__ Wobf, const float* __restrict__ bo,
    float* __restrict__ out_pre, float* __restrict__ stats2) {
  __shared__ unsigned short hnb[32 * HBS];   // B-layout [v][i*3+w] bf16
  __shared__ float a1s[96], b1s[96];
  __shared__ float st1[96], st2[96];
  const int tid = threadIdx.x;
  const int n = blockIdx.x >> 7, t = blockIdx.x & 127;

  if (tid < 96) {
    const float inv = 1.f / (8.f * 128.f * 75.f);
    float m = stats1[tid] * inv;
    float var = stats1[96 + tid] * inv - m * m;
    float a = g1[tid] * rsqrtf(var + EPSB);
    a1s[tid] = a;
    b1s[tid] = bt1[tid] - m * a;
  }
  for (int idx = tid; idx < 7 * HBS; idx += 384)      // zero n-pad rows 25..31
    hnb[25 * HBS + idx] = 0;
  __syncthreads();

  for (int idx = tid; idx < 96 * 75; idx += 384) {
    int i = idx / 75, u = idx - i * 75;
    float hv = h_relu[((n * CB + i) * TB + t) * VLB + u];
    float v = a1s[i] * hv + b1s[i];
    v = v > 0.f ? v : 0.f;
    int w = u / 25, vv = u - w * 25;
    hnb[vv * HBS + i * 3 + w] = f2bf(v);
  }
  __syncthreads();

  const int wave = tid >> 6, lane = tid & 63;
  const int l15 = lane & 15, quad = lane >> 4, q8 = quad * 8;
  const f32x4 zf = {0.f, 0.f, 0.f, 0.f};
  f32x4 acc[2] = {zf, zf};
  const unsigned short* Ap = Wobf + (wave * 16 + l15) * 288 + q8;
#pragma unroll
  for (int kk = 0; kk < 9; ++kk) {
    bf16x8 a = *reinterpret_cast<const bf16x8*>(Ap + kk * 32);
    bf16x8 b0 = *reinterpret_cast<const bf16x8*>(&hnb[l15 * HBS + kk * 32 + q8]);
    bf16x8 b1 = *reinterpret_cast<const bf16x8*>(&hnb[(16 + l15) * HBS + kk * 32 + q8]);
    acc[0] = __builtin_amdgcn_mfma_f32_16x16x32_bf16(a, b0, acc[0], 0, 0, 0);
    acc[1] = __builtin_amdgcn_mfma_f32_16x16x32_bf16(a, b1, acc[1], 0, 0, 0);
  }

  const int orow = wave * 16 + quad * 4;
  float s1[4] = {0.f, 0.f, 0.f, 0.f}, s2[4] = {0.f, 0.f, 0.f, 0.f};
#pragma unroll
  for (int nt = 0; nt < 2; ++nt) {
    int v = nt * 16 + l15;
    if (v < VB) {
#pragma unroll
      for (int r = 0; r < 4; ++r) {
        const int o = orow + r;
        float val = acc[nt][r] + bo[o];
        out_pre[((n * CB + o) * TB + t) * VB + v] = val;
        s1[r] += val;
        s2[r] += val * val;
      }
    }
  }
#pragma unroll
  for (int off = 1; off < 16; off <<= 1) {
#pragma unroll
    for (int r = 0; r < 4; ++r) {
      s1[r] += __shfl_xor(s1[r], off, 64);
      s2[r] += __shfl_xor(s2[r], off, 64);
    }
  }
  if (l15 == 0) {
#pragma unroll
    for (int r = 0; r < 4; ++r) { st1[orow + r] = s1[r]; st2[orow + r] = s2[r]; }
  }
  __syncthreads();
  if (tid < 96) {
    atomicAdd(&stats2[tid], st1[tid]);
    atomicAdd(&stats2[96 + tid], st2[tid]);
  }
}

// ---------------- K5: BN2 finalize (float4 elementwise) ----------------
__global__ __launch_bounds__(256) void k5_bn2(
    const float* __restrict__ out_pre, const float* __restrict__ stats2,
    const float* __restrict__ g2, const float* __restrict__ bt2,
    float* __restrict__ out) {
  int idx = blockIdx.x * 256 + threadIdx.x;          // float4 index
  if (idx >= NB * CB * TB * VB / 4) return;
  int o = (idx / (TB * VB / 4)) % CB;
  const float inv = 1.f / (8.f * 128.f * 25.f);
  float m = stats2[o] * inv;
  float var = stats2[96 + o] * inv - m * m;
  float a = g2[o] * rsqrtf(var + EPSB);
  float b = bt2[o] - m * a;
  f32x4 vin = reinterpret_cast<const f32x4*>(out_pre)[idx];
  f32x4 vo;
#pragma unroll
  for (int j = 0; j < 4; ++j) vo[j] = a * vin[j] + b;
  reinterpret_cast<f32x4*>(out)[idx] = vo;
}

extern "C" void kernel_launch(void* const* d_in, const int* in_sizes, int n_in,
                              void* d_out, int out_size, void* d_ws, size_t ws_size,
                              hipStream_t stream) {
  const float* x   = (const float*)d_in[0];
  const float* As  = (const float*)d_in[1];
  const float* Bs  = (const float*)d_in[2];
  const float* Ar  = (const float*)d_in[3];
  const float* Wm  = (const float*)d_in[4];
  const float* bm  = (const float*)d_in[5];
  const float* g1  = (const float*)d_in[6];
  const float* bt1 = (const float*)d_in[7];
  const float* Wo  = (const float*)d_in[8];
  const float* bo  = (const float*)d_in[9];
  const float* g2  = (const float*)d_in[10];
  const float* bt2 = (const float*)d_in[11];

  float* ws      = (float*)d_ws;
  float* h_relu  = ws;                                     // 7,372,800 f
  float* out_pre = ws + 7372800;                           // 2,457,600 f
  unsigned short* ABbf = (unsigned short*)(ws + 9830400);  // 92,160 us
  unsigned short* Wbf  = ABbf + 92160;                     // 110,592 us
  unsigned short* Wobf = Wbf + 110592;                     // 27,648 us
  float* stats   = (float*)(Wobf + 27648);                 // 384 f
  float* stats1  = stats;
  float* stats2  = stats + 192;
  float* out     = (float*)d_out;

  k0_init<<<(12 * 96 * 96 + 255) / 256, 256, 0, stream>>>(As, Bs, Ar, Wm, Wo, ABbf, Wbf, Wobf, stats);
  k1_mfma<<<NB * TB / 2, 384, 0, stream>>>(x, ABbf, Wbf, bm, h_relu, stats1);
  k3_outconv<<<NB * TB, 384, 0, stream>>>(h_relu, stats1, g1, bt1, Wobf, bo, out_pre, stats2);
  k5_bn2<<<(NB * CB * TB * VB / 4 + 255) / 256, 256, 0, stream>>>(out_pre, stats2, g2, bt2, out);
}

// Round 4
// 238.748 us; speedup vs baseline: 6.9755x; 1.2171x over previous
//
#include <hip/hip_runtime.h>

// MS-G3D block. bf16-MFMA, software-pipelined ps loop in k1.
// N=8, C=96, T=128, V=25, WIN=3, VL=75, NS=6.

#define NB 8
#define CB 96
#define TB 128
#define VB 25
#define VLB 75
#define EPSB 1e-5f
#define XRS 104   // xraw row stride (shorts)
#define TMS 104   // tmp row stride
#define HBS 296   // hnb row stride (shorts)

typedef __attribute__((ext_vector_type(8))) short bf16x8;
typedef __attribute__((ext_vector_type(4))) float f32x4;

__device__ inline unsigned short f2bf(float f) {
  unsigned int u = __float_as_uint(f);
  u = (u + 0x7FFFu + ((u >> 16) & 1u)) >> 16;
  return (unsigned short)u;
}

// ---------------- K0: pre-cast W, AB, Wo to bf16; zero stats ----------------
__global__ __launch_bounds__(256) void k0_init(
    const float* __restrict__ As, const float* __restrict__ Bs,
    const float* __restrict__ Ar, const float* __restrict__ Wm,
    const float* __restrict__ Wo,
    unsigned short* __restrict__ ABbf, unsigned short* __restrict__ Wbf,
    unsigned short* __restrict__ Wobf, float* __restrict__ stats) {
  int i = blockIdx.x * 256 + threadIdx.x;
  if (i < 12 * 96 * 96) {                       // Wbf[ps][o][c]
    int ps = i / 9216, rem = i % 9216, o = rem / 96, c = rem % 96;
    Wbf[i] = f2bf(Wm[o * 1152 + ps * 96 + c]);
  }
  if (i < 12 * 80 * 96) {                       // ABbf[ps][u][u'] (n-major, k contiguous)
    int ps = i / 7680, rem = i % 7680, u = rem / 96, up = rem % 96;
    float v = 0.f;
    if (u < 75 && up < 75) {
      int path = ps / 6, s = ps % 6;
      int idx = (s * 75 + u) * 75 + up;
      v = (path == 0 ? As[idx] : Bs[idx]) + Ar[idx];
    }
    ABbf[i] = f2bf(v);
  }
  if (i < 96 * 288) Wobf[i] = f2bf(Wo[i]);      // (o,i,w) flat == [o][i*3+w]
  if (i < 384) stats[i] = 0.f;
}

// ---------------- K1: unfold + pipelined (MLP -> agg) x12 MFMA --------------
// grid = N*T = 1024 blocks, 384 threads (6 waves). Wave w owns o-rows [16w,16w+16).
// Pipeline: write tmp(ps) -> prefetch b2(ps) -> GEMM1(ps+1) MFMAs -> GEMM2(ps).
// tmp rows are wave-private and DS ops complete in order per wave: no barriers.
__global__ __launch_bounds__(384, 3) void k1_mfma(
    const float* __restrict__ x, const unsigned short* __restrict__ ABbf,
    const unsigned short* __restrict__ Wbf, const float* __restrict__ bm,
    float* __restrict__ h_relu, float* __restrict__ stats1) {
  __shared__ unsigned short xraw[80 * XRS];   // [u'=(w*25+v)][c], rows 75..79 zero
  __shared__ unsigned short tmp_s[96 * TMS];  // [o][u']
  __shared__ float st1s[96], st2s[96];
  const int tid = threadIdx.x;
  const int n = blockIdx.x >> 7, t = blockIdx.x & 127;
  const int wave = tid >> 6, lane = tid & 63;
  const int l15 = lane & 15, quad = lane >> 4, q8 = quad * 8;
  const int wrow16 = wave * 16;

  for (int idx = tid; idx < 96 * 80; idx += 384) {
    int c = idx / 80, r = idx - c * 80;
    float v = 0.f;
    if (r < 75) {
      int tt = t - 1 + r / 25, vv = r % 25;
      if (tt >= 0 && tt < TB) v = x[((n * CB + c) * TB + tt) * VB + vv];
    }
    xraw[r * XRS + c] = f2bf(v);
  }
  // zero own-wave tmp K-pad cols [80,96) (cols 75..79 are written 0 each ps)
  {
    int row = wrow16 + l15;
    int c0 = 80 + quad * 4;
#pragma unroll
    for (int j = 0; j < 4; ++j) tmp_s[row * TMS + c0 + j] = 0;
  }
  __syncthreads();

  const f32x4 zf = {0.f, 0.f, 0.f, 0.f};
  f32x4 acc2[5], acc1[5], acc1n[5];
#pragma unroll
  for (int nt = 0; nt < 5; ++nt) acc2[nt] = zf;

  const unsigned short* Wrow = Wbf + (wrow16 + l15) * 96 + q8;

  // GEMM1 for ps=0
#pragma unroll
  for (int nt = 0; nt < 5; ++nt) acc1[nt] = zf;
#pragma unroll
  for (int kk = 0; kk < 3; ++kk) {
    bf16x8 a = *reinterpret_cast<const bf16x8*>(Wrow + kk * 32);
#pragma unroll
    for (int nt = 0; nt < 5; ++nt) {
      bf16x8 b = *reinterpret_cast<const bf16x8*>(&xraw[(nt * 16 + l15) * XRS + kk * 32 + q8]);
      acc1[nt] = __builtin_amdgcn_mfma_f32_16x16x32_bf16(a, b, acc1[nt], 0, 0, 0);
    }
  }

  for (int ps = 0; ps < 12; ++ps) {
    // (1) write tmp(ps); cols >=75 forced to 0 (K-pad safety)
#pragma unroll
    for (int nt = 0; nt < 5; ++nt) {
      int col = nt * 16 + l15;
#pragma unroll
      for (int r = 0; r < 4; ++r) {
        unsigned short v = (col < 75) ? f2bf(acc1[nt][r]) : (unsigned short)0;
        tmp_s[(wrow16 + quad * 4 + r) * TMS + col] = v;
      }
    }
    // (2) prefetch first b2 batch for GEMM2(ps)
    const unsigned short* Bp = ABbf + ps * 7680 + l15 * 96 + q8;
    bf16x8 bcur[5], bnxt[5];
#pragma unroll
    for (int nt = 0; nt < 5; ++nt)
      bcur[nt] = *reinterpret_cast<const bf16x8*>(Bp + nt * 1536);

    // (3) GEMM1(ps+1): independent MFMA work hides tmp write->read latency
#pragma unroll
    for (int nt = 0; nt < 5; ++nt) acc1n[nt] = zf;
    if (ps < 11) {
      const unsigned short* Wp = Wrow + (ps + 1) * 9216;
#pragma unroll
      for (int kk = 0; kk < 3; ++kk) {
        bf16x8 a = *reinterpret_cast<const bf16x8*>(Wp + kk * 32);
#pragma unroll
        for (int nt = 0; nt < 5; ++nt) {
          bf16x8 b = *reinterpret_cast<const bf16x8*>(&xraw[(nt * 16 + l15) * XRS + kk * 32 + q8]);
          acc1n[nt] = __builtin_amdgcn_mfma_f32_16x16x32_bf16(a, b, acc1n[nt], 0, 0, 0);
        }
      }
    }

    // (4) GEMM2(ps) with 2-stage b2 register prefetch
#pragma unroll
    for (int kk = 0; kk < 3; ++kk) {
      if (kk < 2) {
#pragma unroll
        for (int nt = 0; nt < 5; ++nt)
          bnxt[nt] = *reinterpret_cast<const bf16x8*>(Bp + nt * 1536 + (kk + 1) * 32);
      }
      bf16x8 a2 = *reinterpret_cast<const bf16x8*>(&tmp_s[(wrow16 + l15) * TMS + kk * 32 + q8]);
#pragma unroll
      for (int nt = 0; nt < 5; ++nt)
        acc2[nt] = __builtin_amdgcn_mfma_f32_16x16x32_bf16(a2, bcur[nt], acc2[nt], 0, 0, 0);
      if (kk < 2) {
#pragma unroll
        for (int nt = 0; nt < 5; ++nt) bcur[nt] = bnxt[nt];
      }
    }
#pragma unroll
    for (int nt = 0; nt < 5; ++nt) acc1[nt] = acc1n[nt];
  }

  // epilogue: bias + relu + store + BN1 partial stats
  const int orow = wrow16 + quad * 4;
  float s1[4] = {0.f, 0.f, 0.f, 0.f}, s2[4] = {0.f, 0.f, 0.f, 0.f};
#pragma unroll
  for (int r = 0; r < 4; ++r) {
    const int o = orow + r;
    const float bias = bm[o];
    float* hp = h_relu + ((n * CB + o) * TB + t) * VLB;
#pragma unroll
    for (int nt = 0; nt < 5; ++nt) {
      int u = nt * 16 + l15;
      if (u < VLB) {
        float v = acc2[nt][r] + bias;
        v = v > 0.f ? v : 0.f;
        hp[u] = v;
        s1[r] += v;
        s2[r] += v * v;
      }
    }
  }
#pragma unroll
  for (int off = 1; off < 16; off <<= 1) {
#pragma unroll
    for (int r = 0; r < 4; ++r) {
      s1[r] += __shfl_xor(s1[r], off, 64);
      s2[r] += __shfl_xor(s2[r], off, 64);
    }
  }
  if (l15 == 0) {
#pragma unroll
    for (int r = 0; r < 4; ++r) { st1s[orow + r] = s1[r]; st2s[orow + r] = s2[r]; }
  }
  __syncthreads();
  if (tid < 96) {
    atomicAdd(&stats1[tid], st1s[tid]);
    atomicAdd(&stats1[96 + tid], st2s[tid]);
  }
}

// ---------------- K3: BN1-finalize + relu + out_conv (MFMA, 2 t/blk) --------
// grid = N*T/2 = 512 blocks, 384 threads. out[o,v] = sum_{i,w} Wo[o,i*3+w]*hn[i,w*25+v]
__global__ __launch_bounds__(384) void k3_outconv(
    const float* __restrict__ h_relu, const float* __restrict__ stats1,
    const float* __restrict__ g1, const float* __restrict__ bt1,
    const unsigned short* __restrict__ Wobf, const float* __restrict__ bo,
    float* __restrict__ out_pre, float* __restrict__ stats2) {
  __shared__ unsigned short hnb[2][32 * HBS];   // B-layout [v][i*3+w] bf16, per dt
  __shared__ float a1s[96], b1s[96];
  __shared__ float st1[96], st2[96];
  const int tid = threadIdx.x;
  const int n = blockIdx.x >> 6, t0 = (blockIdx.x & 63) * 2;

  if (tid < 96) {
    const float inv = 1.f / (8.f * 128.f * 75.f);
    float m = stats1[tid] * inv;
    float var = stats1[96 + tid] * inv - m * m;
    float a = g1[tid] * rsqrtf(var + EPSB);
    a1s[tid] = a;
    b1s[tid] = bt1[tid] - m * a;
  }
  for (int idx = tid; idx < 2 * 7 * HBS; idx += 384) {   // zero n-pad rows 25..31
    int d = idx / (7 * HBS), rm = idx % (7 * HBS);
    hnb[d][25 * HBS + rm] = 0;
  }
  __syncthreads();

  for (int idx = tid; idx < 2 * 96 * 75; idx += 384) {
    int d = idx / 7200, rm = idx % 7200;
    int i = rm / 75, u = rm - i * 75;
    float hv = h_relu[((n * CB + i) * TB + t0 + d) * VLB + u];
    float v = a1s[i] * hv + b1s[i];
    v = v > 0.f ? v : 0.f;
    int w = u / 25, vv = u - w * 25;
    hnb[d][vv * HBS + i * 3 + w] = f2bf(v);
  }
  __syncthreads();

  const int wave = tid >> 6, lane = tid & 63;
  const int l15 = lane & 15, quad = lane >> 4, q8 = quad * 8;
  const f32x4 zf = {0.f, 0.f, 0.f, 0.f};
  f32x4 acc[2][2] = {{zf, zf}, {zf, zf}};
  const unsigned short* Ap = Wobf + (wave * 16 + l15) * 288 + q8;
#pragma unroll
  for (int kk = 0; kk < 9; ++kk) {
    bf16x8 a = *reinterpret_cast<const bf16x8*>(Ap + kk * 32);
#pragma unroll
    for (int d = 0; d < 2; ++d) {
      bf16x8 b0 = *reinterpret_cast<const bf16x8*>(&hnb[d][l15 * HBS + kk * 32 + q8]);
      bf16x8 b1 = *reinterpret_cast<const bf16x8*>(&hnb[d][(16 + l15) * HBS + kk * 32 + q8]);
      acc[d][0] = __builtin_amdgcn_mfma_f32_16x16x32_bf16(a, b0, acc[d][0], 0, 0, 0);
      acc[d][1] = __builtin_amdgcn_mfma_f32_16x16x32_bf16(a, b1, acc[d][1], 0, 0, 0);
    }
  }

  const int orow = wave * 16 + quad * 4;
  float s1[4] = {0.f, 0.f, 0.f, 0.f}, s2[4] = {0.f, 0.f, 0.f, 0.f};
#pragma unroll
  for (int d = 0; d < 2; ++d) {
#pragma unroll
    for (int nt = 0; nt < 2; ++nt) {
      int v = nt * 16 + l15;
      if (v < VB) {
#pragma unroll
        for (int r = 0; r < 4; ++r) {
          const int o = orow + r;
          float val = acc[d][nt][r] + bo[o];
          out_pre[((n * CB + o) * TB + t0 + d) * VB + v] = val;
          s1[r] += val;
          s2[r] += val * val;
        }
      }
    }
  }
#pragma unroll
  for (int off = 1; off < 16; off <<= 1) {
#pragma unroll
    for (int r = 0; r < 4; ++r) {
      s1[r] += __shfl_xor(s1[r], off, 64);
      s2[r] += __shfl_xor(s2[r], off, 64);
    }
  }
  if (l15 == 0) {
#pragma unroll
    for (int r = 0; r < 4; ++r) { st1[orow + r] = s1[r]; st2[orow + r] = s2[r]; }
  }
  __syncthreads();
  if (tid < 96) {
    atomicAdd(&stats2[tid], st1[tid]);
    atomicAdd(&stats2[96 + tid], st2[tid]);
  }
}

// ---------------- K5: BN2 finalize (float4 elementwise) ----------------
__global__ __launch_bounds__(256) void k5_bn2(
    const float* __restrict__ out_pre, const float* __restrict__ stats2,
    const float* __restrict__ g2, const float* __restrict__ bt2,
    float* __restrict__ out) {
  int idx = blockIdx.x * 256 + threadIdx.x;          // float4 index
  if (idx >= NB * CB * TB * VB / 4) return;
  int o = (idx / (TB * VB / 4)) % CB;
  const float inv = 1.f / (8.f * 128.f * 25.f);
  float m = stats2[o] * inv;
  float var = stats2[96 + o] * inv - m * m;
  float a = g2[o] * rsqrtf(var + EPSB);
  float b = bt2[o] - m * a;
  f32x4 vin = reinterpret_cast<const f32x4*>(out_pre)[idx];
  f32x4 vo;
#pragma unroll
  for (int j = 0; j < 4; ++j) vo[j] = a * vin[j] + b;
  reinterpret_cast<f32x4*>(out)[idx] = vo;
}

extern "C" void kernel_launch(void* const* d_in, const int* in_sizes, int n_in,
                              void* d_out, int out_size, void* d_ws, size_t ws_size,
                              hipStream_t stream) {
  const float* x   = (const float*)d_in[0];
  const float* As  = (const float*)d_in[1];
  const float* Bs  = (const float*)d_in[2];
  const float* Ar  = (const float*)d_in[3];
  const float* Wm  = (const float*)d_in[4];
  const float* bm  = (const float*)d_in[5];
  const float* g1  = (const float*)d_in[6];
  const float* bt1 = (const float*)d_in[7];
  const float* Wo  = (const float*)d_in[8];
  const float* bo  = (const float*)d_in[9];
  const float* g2  = (const float*)d_in[10];
  const float* bt2 = (const float*)d_in[11];

  float* ws      = (float*)d_ws;
  float* h_relu  = ws;                                     // 7,372,800 f
  float* out_pre = ws + 7372800;                           // 2,457,600 f
  unsigned short* ABbf = (unsigned short*)(ws + 9830400);  // 92,160 us
  unsigned short* Wbf  = ABbf + 92160;                     // 110,592 us
  unsigned short* Wobf = Wbf + 110592;                     // 27,648 us
  float* stats   = (float*)(Wobf + 27648);                 // 384 f
  float* stats1  = stats;
  float* stats2  = stats + 192;
  float* out     = (float*)d_out;

  k0_init<<<(12 * 96 * 96 + 255) / 256, 256, 0, stream>>>(As, Bs, Ar, Wm, Wo, ABbf, Wbf, Wobf, stats);
  k1_mfma<<<NB * TB, 384, 0, stream>>>(x, ABbf, Wbf, bm, h_relu, stats1);
  k3_outconv<<<NB * TB / 2, 384, 0, stream>>>(h_relu, stats1, g1, bt1, Wobf, bo, out_pre, stats2);
  k5_bn2<<<(NB * CB * TB * VB / 4 + 255) / 256, 256, 0, stream>>>(out_pre, stats2, g2, bt2, out);
}